// Round 13
// baseline (86.059 us; speedup 1.0000x reference)
//
#include <hip/hip_runtime.h>
#include <hip/hip_bf16.h>
#include <math.h>

// Problem constants
#define BATCH   2048
#define TWO_B   4096
#define DIM     1024
#define NTRI    136           // upper-triangle tiles of the 16x16 grid
#define RBLK    32            // reduce blocks
// 1 / (0.07 * ln(2)) : exp(s/T) = exp2(s * INV_T_LOG2E)
#define INV_T_LOG2E 20.60991907f
#define INV_T       14.285714285714286f
#define INV_127SQ   6.200013640958517e-05f   // 1/(127*127)

typedef float f32x4 __attribute__((ext_vector_type(4)));
typedef int   i32x4 __attribute__((ext_vector_type(4)));

// R26: triangle symmetry. R25 verdict: staging is service-rate-bound
// (depth-3 neutral-to-worse). Open question: per-CU rate (~10-12 B/cyc,
// but m97 proved 21 B/cyc possible) vs aggregate/same-line contention
// (8 CUs/XCD reading identical panel lines). All prior rounds kept 256
// CUs busy so the regimes are indistinguishable. sim is BIT-EXACT
// symmetric in i8 -> compute 136 upper-triangle tiles only; off-diagonal
// blocks emit row-pass AND col-pass exp-sums from the same exp2 values.
// Halves total staged bytes 134->70 MB. If contention-bound: gemm ~32->
// ~20-24. If per-CU-bound: neutral -> regime resolved, fp4 next.
__device__ __attribute__((aligned(4096))) char g_z[(size_t)TWO_B * DIM]; // i8 tiled, 4 MB
__device__ __attribute__((aligned(256))) float g_part[TWO_B][32];        // 512 KB
__device__ float        g_positives[TWO_B];   // rows 0..2047 written; [r]==[r^2048]
__device__ float        g_loss;
__device__ unsigned int g_counter;

__device__ __forceinline__ void load_lds16(const void* g, void* l) {
    __builtin_amdgcn_global_load_lds(
        (const __attribute__((address_space(1))) void*)g,
        (__attribute__((address_space(3))) void*)l,
        16, 0, 0);
}

// ---------------------------------------------------------------------------
// Kernel 1: L2-normalize 4096 rows -> int8, k-tiled + pre-swizzled layout:
// lane's 16 B (kt=lane>>2, seg s=lane&3) ->
//   z_t[(row>>8)*16 + kt][(row>>4)&15][row&15][s ^ ((row&15)>>1)&3]
// ---------------------------------------------------------------------------
__global__ __launch_bounds__(256) void normalize_kernel(
        const float* __restrict__ feat) {
    const int lane = threadIdx.x & 63;
    const int row  = blockIdx.x * 4 + (threadIdx.x >> 6);
    if (blockIdx.x == 0 && threadIdx.x == 0) { g_loss = 0.0f; g_counter = 0u; }

    const float* src = feat + (row < BATCH ? (size_t)row * (2 * DIM)
                                           : (size_t)(row - BATCH) * (2 * DIM) + DIM);
    float4 v[4];
    float ss = 0.0f;
    #pragma unroll
    for (int t = 0; t < 4; ++t) {
        v[t] = ((const float4*)src)[t * 64 + lane];
        ss += v[t].x * v[t].x + v[t].y * v[t].y + v[t].z * v[t].z + v[t].w * v[t].w;
    }
    #pragma unroll
    for (int off = 32; off; off >>= 1) ss += __shfl_xor(ss, off, 64);
    const float s127 = 127.0f / fmaxf(sqrtf(ss), 1e-12f);
    int4 o;
    int* op = (int*)&o;
    #pragma unroll
    for (int t = 0; t < 4; ++t) {
        const int b0 = __float2int_rn(v[t].x * s127) & 255;
        const int b1 = __float2int_rn(v[t].y * s127) & 255;
        const int b2 = __float2int_rn(v[t].z * s127) & 255;
        const int b3 = __float2int_rn(v[t].w * s127) & 255;
        op[t] = b0 | (b1 << 8) | (b2 << 16) | (b3 << 24);
    }
    const int kt = lane >> 2;
    const int s  = lane & 3;
    const int rl = row & 15;
    const int m  = (rl >> 1) & 3;
    const size_t off = ((size_t)((row >> 8) * 16 + kt) << 14)
                     + ((size_t)((row >> 4) & 15) << 10)
                     + (rl << 6) + ((s ^ m) << 4);
    *(int4*)(g_z + off) = o;
}

// ---------------------------------------------------------------------------
// Kernel 2 (R26): triangle gemm. K-loop = R24 exact (3-buffer, depth-2,
// counted vmcnt). Epilogue: row-pass slots 2(bx-by)+wc; col-pass (off-diag
// only) reduces over rows (i,reg local; q via shfl 16/32; wr via LDS patch
// at smem+96K) into slot 2(16-bx)+by of the COL-range rows. Slot ranges
// are disjoint; row-tile T uses slots 0..31-T.
// ---------------------------------------------------------------------------
__global__ __launch_bounds__(512) void gemm_fused() {
    __shared__ char smem[102400];    // 3 staging buffers (96 KB) + 4 KB sC

    // triangle enumeration: bid -> (by, bx), by <= bx
    int by = 0, rem = blockIdx.x;
    while (rem >= 16 - by) { rem -= 16 - by; ++by; }
    const int bx = by + rem;
    const bool diag = (by == bx);
    const int rb  = by * 256;
    const int cb  = bx * 256;

    const int tid  = threadIdx.x;
    const int lane = tid & 63;
    const int wv   = tid >> 6;       // wave 0..7
    const int wr   = wv & 3;         // wave row (0..3) -> 64-row subtile
    const int wc   = wv >> 2;        // wave col (0..1) -> 128-col subtile
    const int q    = lane >> 4;      // quad 0..3
    const int mn   = lane & 15;

    i32x4 acc[4][8] = {};            // i32 accumulators (exact)

    const int rslot = (q ^ ((mn >> 1) & 3)) * 16;      // LDS read XOR (unchanged)

    // staging: 32 chunks of 1 KB (A: ci 0..15 from slab by*16+kt,
    // B: ci 16..31 from slab bx*16+kt); wave wv stages ci = 4wv..4wv+3.
    size_t goff[4];
    int    loff[4];
    #pragma unroll
    for (int t = 0; t < 4; ++t) {
        const int ci = wv * 4 + t;
        const bool isB = ci >= 16;
        const int  cc  = ci & 15;
        goff[t] = ((size_t)((isB ? bx : by) * 16) << 14)   // slab base (kt=0)
                + ((size_t)cc << 10) + (size_t)lane * 16;
        loff[t] = (isB ? 16384 : 0) + cc * 1024;
    }

    // ---- prologue: stage tiles 0,1 into buffers 0,1; wait tile 0 only ----
    #pragma unroll
    for (int b = 0; b < 2; ++b)
        #pragma unroll
        for (int t = 0; t < 4; ++t)
            load_lds16(g_z + goff[t] + (size_t)b * 16384, smem + b * 32768 + loff[t]);
    asm volatile("s_waitcnt vmcnt(4)" ::: "memory");   // tile 0 resident
    __builtin_amdgcn_s_barrier();

    int cur = 0;                     // buffer holding tile t
    for (int t = 0; t < 16; ++t) {
        const char* cA = smem + cur * 32768;
        const char* cB = cA + 16384;

        i32x4 af[4], bf[8];
        #pragma unroll
        for (int i = 0; i < 4; ++i)
            af[i] = *(const i32x4*)&cA[(wr * 64 + i * 16 + mn) * 64 + rslot];
        #pragma unroll
        for (int j = 0; j < 8; ++j)
            bf[j] = *(const i32x4*)&cB[(wc * 128 + j * 16 + mn) * 64 + rslot];

        if (t + 2 < 16) {            // stage tile t+2 into buf (cur+2)%3
            const int bs = cur >= 1 ? cur - 1 : 2;
            #pragma unroll
            for (int tt = 0; tt < 4; ++tt)
                load_lds16(g_z + goff[tt] + (size_t)(t + 2) * 16384,
                           smem + bs * 32768 + loff[tt]);
        }

        #pragma unroll
        for (int i = 0; i < 4; ++i)
            #pragma unroll
            for (int j = 0; j < 8; ++j)
                acc[i][j] = __builtin_amdgcn_mfma_i32_16x16x64_i8(
                                af[i], bf[j], acc[i][j], 0, 0, 0);

        if (t < 15) {
            if (t < 14) asm volatile("s_waitcnt vmcnt(4) lgkmcnt(0)" ::: "memory");
            else        asm volatile("s_waitcnt vmcnt(0) lgkmcnt(0)" ::: "memory");
            __builtin_amdgcn_s_barrier();
        }
        cur = cur == 2 ? 0 : cur + 1;
    }

    // ---- Epilogue: row-pass + (off-diag) col-pass from shared exp2 ----
    float col_acc[8] = {0.f, 0.f, 0.f, 0.f, 0.f, 0.f, 0.f, 0.f};
    const int rowslot = (bx - by) * 2 + wc;   // row-tile by, slots 0..31-2*by span
    #pragma unroll
    for (int i = 0; i < 4; ++i) {
        #pragma unroll
        for (int reg = 0; reg < 4; ++reg) {
            const int r  = rb + wr * 64 + i * 16 + q * 4 + reg;
            const int pc = (r + BATCH) & (TWO_B - 1);
            float local = 0.0f;
            #pragma unroll
            for (int j = 0; j < 8; ++j) {
                const int c = cb + wc * 128 + j * 16 + mn;
                const float s = (float)acc[i][j][reg] * INV_127SQ;
                if (c == pc)   // only blocks (T,T+8) hit; writes rows 0..2047 once
                    g_positives[r] = s;
                const float e = (c == r) ? 0.0f : exp2f(s * INV_T_LOG2E);
                local += e;
                col_acc[j] += e;
            }
            local += __shfl_xor(local, 1, 64);
            local += __shfl_xor(local, 2, 64);
            local += __shfl_xor(local, 4, 64);
            local += __shfl_xor(local, 8, 64);
            if (mn == 0) g_part[r][rowslot] = local;
        }
    }

    if (!diag) {
        // fold q (rows within wave): lanes with same mn, different q
        #pragma unroll
        for (int j = 0; j < 8; ++j) {
            col_acc[j] += __shfl_xor(col_acc[j], 16, 64);
            col_acc[j] += __shfl_xor(col_acc[j], 32, 64);
        }
        float* sC = (float*)(smem + 98304);     // [8][8][16] floats, 4 KB
        if (q == 0) {
            #pragma unroll
            for (int j = 0; j < 8; ++j)
                sC[(wv * 8 + j) * 16 + mn] = col_acc[j];
        }
        __syncthreads();
        if (tid < 256) {                        // one thread per column
            const int col = tid;                // wc2*128 + j2*16 + mn2
            const int wc2 = col >> 7, j2 = (col >> 4) & 7, mn2 = col & 15;
            float s4 = 0.0f;
            #pragma unroll
            for (int w = 0; w < 4; ++w)         // wv = wc2*4 + wr
                s4 += sC[((wc2 * 4 + w) * 8 + j2) * 16 + mn2];
            g_part[cb + col][2 * (16 - bx) + by] = s4;   // col-pass slot
        }
    }
}

// ---------------------------------------------------------------------------
// Kernel 3: parallel reduce — row-tile T has 32-T valid slots.
// positives symmetric: read [r & 2047].
// ---------------------------------------------------------------------------
__global__ __launch_bounds__(128) void reduce_kernel(float* __restrict__ out) {
    const int tid = threadIdx.x;
    const int r   = blockIdx.x * 128 + tid;
    const int n   = 32 - (r >> 8);
    float s = 0.0f;
    for (int u = 0; u < n; ++u) s += g_part[r][u];
    float acc = logf(s) - g_positives[r & (BATCH - 1)] * INV_T;
    #pragma unroll
    for (int off = 32; off; off >>= 1) acc += __shfl_down(acc, off, 64);
    __shared__ float sp[2];
    __shared__ int amLast;
    if ((tid & 63) == 0) sp[tid >> 6] = acc;
    __syncthreads();
    if (tid == 0) {
        atomicAdd(&g_loss, sp[0] + sp[1]);
        unsigned int old = __hip_atomic_fetch_add(&g_counter, 1u, __ATOMIC_RELAXED,
                                                  __HIP_MEMORY_SCOPE_AGENT);
        amLast = (old == RBLK - 1);
    }
    __syncthreads();
    if (amLast && tid == 0)
        out[0] = __hip_atomic_load(&g_loss, __ATOMIC_RELAXED,
                                   __HIP_MEMORY_SCOPE_AGENT) * (1.0f / TWO_B);
}

extern "C" void kernel_launch(void* const* d_in, const int* in_sizes, int n_in,
                              void* d_out, int out_size, void* d_ws, size_t ws_size,
                              hipStream_t stream) {
    const float* feat = (const float*)d_in[0];
    float* out = (float*)d_out;
    (void)d_ws; (void)ws_size;   // poison fill is unconditional (R14) — ws unused

    normalize_kernel<<<TWO_B / 4, 256, 0, stream>>>(feat);
    gemm_fused<<<NTRI, 512, 0, stream>>>();
    reduce_kernel<<<RBLK, 128, 0, stream>>>(out);
}

// Round 14
// 85.087 us; speedup vs baseline: 1.0114x; 1.0114x over previous
//
#include <hip/hip_runtime.h>
#include <hip/hip_bf16.h>
#include <math.h>

// Problem constants
#define BATCH   2048
#define TWO_B   4096
#define DIM     1024
#define NBLK4   256           // 16x16 grid of 256x256 tiles
#define RBLK    32            // reduce blocks
// 1 / (0.07 * ln(2)) : exp(s/T) = exp2(s * INV_T_LOG2E)
#define INV_T_LOG2E 20.60991907f
#define INV_T       14.285714285714286f
#define INV_127SQ   6.200013640958517e-05f   // 1/(127*127)

typedef float f32x4 __attribute__((ext_vector_type(4)));
typedef int   i32x4 __attribute__((ext_vector_type(4)));

// R27 = R24 verbatim (measured session best, 83.9 us). Session ledger:
// - fill 43 us: harness-unconditional d_ws poison (R14), 76% HBM peak.
// - normalize 3.5 us: ~94% HBM roofline.
// - gemm ~28 us: per-CU VMEM pull-rate bound (~10-12 B/cyc/CU), confirmed
//   across 6 structures (R18/R19/R23/R24/R25/R26); per-CU bytes minimized
//   at 256^2 (512 KB/CU); triangle/depth-3 neutral (R26/R25).
// - reduce ~2-3 us + launch gaps.
__device__ __attribute__((aligned(4096))) char g_z[(size_t)TWO_B * DIM]; // i8 tiled, 4 MB
__device__ __attribute__((aligned(256))) float g_part[TWO_B][32];        // 512 KB
__device__ float        g_positives[TWO_B];
__device__ float        g_loss;
__device__ unsigned int g_counter;

__device__ __forceinline__ void load_lds16(const void* g, void* l) {
    __builtin_amdgcn_global_load_lds(
        (const __attribute__((address_space(1))) void*)g,
        (__attribute__((address_space(3))) void*)l,
        16, 0, 0);
}

// ---------------------------------------------------------------------------
// Kernel 1: L2-normalize 4096 rows -> int8, k-tiled + pre-swizzled layout:
// lane's 16 B (kt=lane>>2, seg s=lane&3) ->
//   z_t[(row>>8)*16 + kt][(row>>4)&15][row&15][s ^ ((row&15)>>1)&3]
// ---------------------------------------------------------------------------
__global__ __launch_bounds__(256) void normalize_kernel(
        const float* __restrict__ feat) {
    const int lane = threadIdx.x & 63;
    const int row  = blockIdx.x * 4 + (threadIdx.x >> 6);
    if (blockIdx.x == 0 && threadIdx.x == 0) { g_loss = 0.0f; g_counter = 0u; }

    const float* src = feat + (row < BATCH ? (size_t)row * (2 * DIM)
                                           : (size_t)(row - BATCH) * (2 * DIM) + DIM);
    float4 v[4];
    float ss = 0.0f;
    #pragma unroll
    for (int t = 0; t < 4; ++t) {
        v[t] = ((const float4*)src)[t * 64 + lane];
        ss += v[t].x * v[t].x + v[t].y * v[t].y + v[t].z * v[t].z + v[t].w * v[t].w;
    }
    #pragma unroll
    for (int off = 32; off; off >>= 1) ss += __shfl_xor(ss, off, 64);
    const float s127 = 127.0f / fmaxf(sqrtf(ss), 1e-12f);
    int4 o;
    int* op = (int*)&o;
    #pragma unroll
    for (int t = 0; t < 4; ++t) {
        const int b0 = __float2int_rn(v[t].x * s127) & 255;
        const int b1 = __float2int_rn(v[t].y * s127) & 255;
        const int b2 = __float2int_rn(v[t].z * s127) & 255;
        const int b3 = __float2int_rn(v[t].w * s127) & 255;
        op[t] = b0 | (b1 << 8) | (b2 << 16) | (b3 << 24);
    }
    const int kt = lane >> 2;
    const int s  = lane & 3;
    const int rl = row & 15;
    const int m  = (rl >> 1) & 3;
    const size_t off = ((size_t)((row >> 8) * 16 + kt) << 14)
                     + ((size_t)((row >> 4) & 15) << 10)
                     + (rl << 6) + ((s ^ m) << 4);
    *(int4*)(g_z + off) = o;
}

// ---------------------------------------------------------------------------
// Kernel 2: sim = (q q^T)/127^2 via mfma_i32_16x16x64_i8.
// 3-buffer, depth-2 prefetch, counted vmcnt (R23), tiled contiguous
// staging (R24): each staging instruction reads 1 KB contiguous from slab
// ((isB?bx:by)*16 + kt); per-tile advance = +16384. Atomic-free epilogue.
// ---------------------------------------------------------------------------
__global__ __launch_bounds__(512) void gemm_fused() {
    __shared__ char smem[98304];     // 3 buffers x 32 KB [sA 16K | sB 16K]

    // XCD-aware swizzle: id&7 = round-robin XCD; 4x8-tile region per XCD
    const int bid = blockIdx.x;
    const int xcd = bid & 7;
    const int t5  = bid >> 3;                   // 0..31 within region
    const int by  = (xcd >> 1) * 4 + (t5 & 3);
    const int bx  = (xcd & 1) * 8 + (t5 >> 2);
    const int rb  = by * 256;
    const int cb  = bx * 256;

    const int tid  = threadIdx.x;
    const int lane = tid & 63;
    const int wv   = tid >> 6;       // wave 0..7
    const int wr   = wv & 3;         // wave row (0..3) -> 64-row subtile
    const int wc   = wv >> 2;        // wave col (0..1) -> 128-col subtile
    const int q    = lane >> 4;      // quad 0..3
    const int mn   = lane & 15;

    i32x4 acc[4][8] = {};            // i32 accumulators (exact)

    const int rslot = (q ^ ((mn >> 1) & 3)) * 16;      // LDS read XOR

    // staging: 32 chunks of 1 KB (A: ci 0..15 from slab by*16+kt,
    // B: ci 16..31 from slab bx*16+kt); wave wv stages ci = 4wv..4wv+3.
    size_t goff[4];
    int    loff[4];
    #pragma unroll
    for (int t = 0; t < 4; ++t) {
        const int ci = wv * 4 + t;
        const bool isB = ci >= 16;
        const int  cc  = ci & 15;
        goff[t] = ((size_t)((isB ? bx : by) * 16) << 14)   // slab base (kt=0)
                + ((size_t)cc << 10) + (size_t)lane * 16;
        loff[t] = (isB ? 16384 : 0) + cc * 1024;
    }

    // ---- prologue: stage tiles 0,1 into buffers 0,1; wait tile 0 only ----
    #pragma unroll
    for (int b = 0; b < 2; ++b)
        #pragma unroll
        for (int t = 0; t < 4; ++t)
            load_lds16(g_z + goff[t] + (size_t)b * 16384, smem + b * 32768 + loff[t]);
    asm volatile("s_waitcnt vmcnt(4)" ::: "memory");   // tile 0 resident
    __builtin_amdgcn_s_barrier();

    int cur = 0;                     // buffer holding tile t
    for (int t = 0; t < 16; ++t) {
        const char* cA = smem + cur * 32768;
        const char* cB = cA + 16384;

        i32x4 af[4], bf[8];
        #pragma unroll
        for (int i = 0; i < 4; ++i)
            af[i] = *(const i32x4*)&cA[(wr * 64 + i * 16 + mn) * 64 + rslot];
        #pragma unroll
        for (int j = 0; j < 8; ++j)
            bf[j] = *(const i32x4*)&cB[(wc * 128 + j * 16 + mn) * 64 + rslot];

        if (t + 2 < 16) {            // stage tile t+2 into buf (cur+2)%3
            const int bs = cur >= 1 ? cur - 1 : 2;
            #pragma unroll
            for (int tt = 0; tt < 4; ++tt)
                load_lds16(g_z + goff[tt] + (size_t)(t + 2) * 16384,
                           smem + bs * 32768 + loff[tt]);
        }

        #pragma unroll
        for (int i = 0; i < 4; ++i)
            #pragma unroll
            for (int j = 0; j < 8; ++j)
                acc[i][j] = __builtin_amdgcn_mfma_i32_16x16x64_i8(
                                af[i], bf[j], acc[i][j], 0, 0, 0);

        if (t < 15) {
            // tile t+1 must be resident past this barrier; newest in-flight
            // loads are tile t+2's 4 (none issued at t=14 -> drain 0).
            if (t < 14) asm volatile("s_waitcnt vmcnt(4) lgkmcnt(0)" ::: "memory");
            else        asm volatile("s_waitcnt vmcnt(0) lgkmcnt(0)" ::: "memory");
            __builtin_amdgcn_s_barrier();
        }
        cur = cur == 2 ? 0 : cur + 1;
    }

    // ---- Epilogue: exp-sum partials, plain uncontended stores ----
    const int slot = bx * 2 + wc;    // 0..31, unique per (col-tile, half)
    #pragma unroll
    for (int i = 0; i < 4; ++i) {
        #pragma unroll
        for (int reg = 0; reg < 4; ++reg) {
            const int r  = rb + wr * 64 + i * 16 + q * 4 + reg;
            const int pc = (r + BATCH) & (TWO_B - 1);
            float local = 0.0f;
            #pragma unroll
            for (int j = 0; j < 8; ++j) {
                const int c = cb + wc * 128 + j * 16 + mn;
                const float s = (float)acc[i][j][reg] * INV_127SQ;
                if (c == pc)   // unique writer per r across the whole grid
                    g_positives[r] = s;
                local += (c == r) ? 0.0f : exp2f(s * INV_T_LOG2E);
            }
            local += __shfl_xor(local, 1, 64);
            local += __shfl_xor(local, 2, 64);
            local += __shfl_xor(local, 4, 64);
            local += __shfl_xor(local, 8, 64);
            if (mn == 0) g_part[r][slot] = local;   // unique (r, slot)
        }
    }
}

// ---------------------------------------------------------------------------
// Kernel 3: parallel reduce — 32 blocks x 128 threads, one row per thread.
// Finalize tail: 32 agent-scope atomicAdds + relaxed counter (proven).
// ---------------------------------------------------------------------------
__global__ __launch_bounds__(128) void reduce_kernel(float* __restrict__ out) {
    const int tid = threadIdx.x;
    const int r   = blockIdx.x * 128 + tid;
    const float4* pr = (const float4*)g_part[r];
    float s = 0.0f;
    #pragma unroll
    for (int u = 0; u < 8; ++u) {
        const float4 v = pr[u];
        s += v.x + v.y + v.z + v.w;
    }
    float acc = logf(s) - g_positives[r] * INV_T;
    #pragma unroll
    for (int off = 32; off; off >>= 1) acc += __shfl_down(acc, off, 64);
    __shared__ float sp[2];
    __shared__ int amLast;
    if ((tid & 63) == 0) sp[tid >> 6] = acc;
    __syncthreads();
    if (tid == 0) {
        atomicAdd(&g_loss, sp[0] + sp[1]);
        unsigned int old = __hip_atomic_fetch_add(&g_counter, 1u, __ATOMIC_RELAXED,
                                                  __HIP_MEMORY_SCOPE_AGENT);
        amLast = (old == RBLK - 1);
    }
    __syncthreads();
    if (amLast && tid == 0)
        out[0] = __hip_atomic_load(&g_loss, __ATOMIC_RELAXED,
                                   __HIP_MEMORY_SCOPE_AGENT) * (1.0f / TWO_B);
}

extern "C" void kernel_launch(void* const* d_in, const int* in_sizes, int n_in,
                              void* d_out, int out_size, void* d_ws, size_t ws_size,
                              hipStream_t stream) {
    const float* feat = (const float*)d_in[0];
    float* out = (float*)d_out;
    (void)d_ws; (void)ws_size;   // poison fill is unconditional (R14) — ws unused

    normalize_kernel<<<TWO_B / 4, 256, 0, stream>>>(feat);
    gemm_fused<<<NBLK4, 512, 0, stream>>>();
    reduce_kernel<<<RBLK, 128, 0, stream>>>(out);
}